// Round 10
// baseline (3372.239 us; speedup 1.0000x reference)
//
#include <hip/hip_runtime.h>
#include <hip/hip_bf16.h>

#define H 1000
#define B 64
#define S 512
#define D 2000   // 2H
#define KP 2048  // padded K
#define NP 1024  // padded N (h dim)
#define MP 32768 // B*S
#define KS 10    // k-splits for dense

typedef __attribute__((ext_vector_type(8))) short short8;
typedef __attribute__((ext_vector_type(4))) float f32x4;
typedef __attribute__((ext_vector_type(16))) float f32x16;

__device__ inline unsigned short f2bf(float f) {
  __hip_bfloat16 h = __float2bfloat16(f);  // RNE
  union { __hip_bfloat16 h; unsigned short u; } c; c.h = h;
  return c.u;
}
__device__ inline float bf2f(unsigned short u) {
  union { unsigned u; float f; } x; x.u = ((unsigned)u) << 16;
  return x.f;
}
// exact at +/-inf; ~1e-7 rel err; much cheaper than tanhf
__device__ inline float tanh_fast(float x) {
  float e2 = __expf(2.f * x);
  return 1.f - 2.f / (e2 + 1.f);
}

// K0a: dec (B,H) -> dec_t (H,B)
__global__ __launch_bounds__(256) void k_dect(const float* __restrict__ dec,
                                              float* __restrict__ dec_t) {
  const int d = blockIdx.x * 4 + (threadIdx.x >> 6);
  const int b = threadIdx.x & 63;
  dec_t[d * 64 + b] = dec[b * H + d];
}

// K0b: hidden_in[b,h] = sum_d W_b[h,d] * dec[b,d]. Wave per h, lane = b.
__global__ __launch_bounds__(256) void k_hidden2(const float* __restrict__ dec_t,
                                                 const float* __restrict__ Wb,
                                                 float* __restrict__ hi) {
  const int h = blockIdx.x * 4 + (threadIdx.x >> 6);
  const int lane = threadIdx.x & 63;
  const float* w = Wb + (size_t)h * H;
  float acc = 0.f;
#pragma unroll 4
  for (int d = 0; d < H; ++d) acc += w[d] * dec_t[d * 64 + lane];
  hi[lane * H + h] = acc;
}

// K0 fallback
__global__ __launch_bounds__(256) void k_hidden(const float* __restrict__ dec,
                                                const float* __restrict__ Wb,
                                                float* __restrict__ hi) {
  __shared__ float sdec[H];
  const int b = blockIdx.y;
  const int h = blockIdx.x * 4 + (threadIdx.x >> 6);
  const int lane = threadIdx.x & 63;
  for (int d = threadIdx.x; d < H; d += 256) sdec[d] = dec[b * H + d];
  __syncthreads();
  const float* w = Wb + (size_t)h * H;
  float acc = 0.f;
  for (int d = lane; d < H; d += 64) acc += w[d] * sdec[d];
  for (int o = 32; o; o >>= 1) acc += __shfl_xor(acc, o);
  if (lane == 0) hi[b * H + h] = acc;
}

// Pre-pass (both inputs in one launch): fp32 row-major [rows][2000] -> bf16 TILED
// chunks [p(4)][row(256)][8], chunk base (rp*64+t)*8192. Direct reg->global,
// no LDS, no barriers. grid (132, 8): x<128 -> ctx panel, else Wa panel.
__global__ __launch_bounds__(256) void k_cvt2(const float* __restrict__ ctx,
                                              const float* __restrict__ wa,
                                              unsigned short* __restrict__ ctx_b,
                                              unsigned short* __restrict__ wa_b) {
  const int bp = blockIdx.x;
  const float* src;
  unsigned short* dst;
  int valid_rows, rp;
  if (bp < 128) { src = ctx; dst = ctx_b; valid_rows = MP; rp = bp; }
  else          { src = wa;  dst = wa_b;  valid_rows = H;  rp = bp - 128; }
  const int tid = threadIdx.x;
  const int r0 = tid >> 2;   // 0..63
  const int kq = tid & 3;    // plane
  const int t0 = blockIdx.y * 8;
  for (int tt = 0; tt < 8; ++tt) {
    const int t = t0 + tt;
    const int gcol = t * 32 + kq * 8;
    unsigned short* ob = dst + ((size_t)rp * 64 + t) * 8192;
#pragma unroll
    for (int w = 0; w < 4; ++w) {
      const int grow = rp * 256 + r0 + w * 64;
      unsigned short v[8];
      if (grow < valid_rows && gcol + 8 <= D) {
        const float* p = src + (size_t)grow * D + gcol;
        float4 x = *(const float4*)p;
        float4 y = *(const float4*)(p + 4);
        v[0] = f2bf(x.x); v[1] = f2bf(x.y); v[2] = f2bf(x.z); v[3] = f2bf(x.w);
        v[4] = f2bf(y.x); v[5] = f2bf(y.y); v[6] = f2bf(y.z); v[7] = f2bf(y.w);
      } else {
#pragma unroll
        for (int z = 0; z < 8; ++z) v[z] = 0;
      }
      *(short8*)(ob + (kq * 256 + r0 + w * 64) * 8) = *(short8*)&v[0];
    }
  }
}

// K1 fast: 256x256 tile, 16 waves (4x4), mfma_32x32x16, wave tile 64x64 (2x2).
// 2-buffer double-buffered (64 KB LDS) -> 2 blocks/CU = 8 waves/SIMD;
// cross-block overlap hides the per-iter vmcnt(0) drain (m97/m114 mechanism).
__global__ __launch_bounds__(1024, 8) void k_scores_fast(const unsigned short* __restrict__ ctxb,
                                                         const unsigned short* __restrict__ wab,
                                                         const float* __restrict__ hi,
                                                         const float* __restrict__ Wcw,
                                                         float* __restrict__ scores) {
  __shared__ unsigned short As[2][8192];
  __shared__ unsigned short Bs[2][8192];

  // bijective XCD swizzle: 512 blocks = 8 chunks of 64; 4 ctiles of one rtile
  // adjacent -> A-panel L2 reuse.
  const int bid = blockIdx.x;
  const int swz = (bid & 7) * 64 + (bid >> 3);
  const int rtile = swz >> 2;  // 0..127
  const int ctile = swz & 3;   // 0..3
  const int row0 = rtile * 256;
  const int col0 = ctile * 256;

  const int tid = threadIdx.x;
  const int lane = tid & 63;
  const int wid = tid >> 6;        // 0..15
  const int wm = wid >> 2;         // 0..3 (row quarter)
  const int wn = wid & 3;          // 0..3 (col quarter)
  const int ln31 = lane & 31;
  const int kh = lane >> 5;        // 0..1

  const unsigned short* ga = ctxb + (size_t)rtile * (64 * 8192);
  const unsigned short* gb = wab + (size_t)ctile * (64 * 8192);

  f32x16 acc[2][2];
#pragma unroll
  for (int i = 0; i < 2; ++i)
#pragma unroll
    for (int j = 0; j < 2; ++j)
#pragma unroll
      for (int r = 0; r < 16; ++r) acc[i][j][r] = 0.f;

#define STAGE(T, BUF)                                                                                      \
  do {                                                                                                     \
    const unsigned short* pa = ga + (size_t)(T) * 8192 + tid * 8;                                          \
    const unsigned short* pb = gb + (size_t)(T) * 8192 + tid * 8;                                          \
    __builtin_amdgcn_global_load_lds((const __attribute__((address_space(1))) unsigned int*)pa,            \
                                     (__attribute__((address_space(3))) unsigned int*)&As[BUF][tid * 8],   \
                                     16, 0, 0);                                                            \
    __builtin_amdgcn_global_load_lds((const __attribute__((address_space(1))) unsigned int*)pb,            \
                                     (__attribute__((address_space(3))) unsigned int*)&Bs[BUF][tid * 8],   \
                                     16, 0, 0);                                                            \
  } while (0)

  // plane p = ks*2 + kh; addr(shorts) = p*2048 + row*8
  const int abase = kh * 2048 + (wm * 64 + ln31) * 8;
  const int bbase = kh * 2048 + (wn * 64 + ln31) * 8;

#define COMPUTE(BI)                                                                     \
  do {                                                                                  \
    _Pragma("unroll")                                                                   \
    for (int ks = 0; ks < 2; ++ks) {                                                    \
      short8 a[2], bb[2];                                                               \
      _Pragma("unroll")                                                                 \
      for (int mi = 0; mi < 2; ++mi)                                                    \
        a[mi] = *(const short8*)&As[BI][abase + ks * 4096 + mi * 256];                  \
      _Pragma("unroll")                                                                 \
      for (int ni = 0; ni < 2; ++ni)                                                    \
        bb[ni] = *(const short8*)&Bs[BI][bbase + ks * 4096 + ni * 256];                 \
      __builtin_amdgcn_s_setprio(1);                                                    \
      _Pragma("unroll")                                                                 \
      for (int mi = 0; mi < 2; ++mi)                                                    \
        _Pragma("unroll")                                                               \
        for (int ni = 0; ni < 2; ++ni)                                                  \
          acc[mi][ni] = __builtin_amdgcn_mfma_f32_32x32x16_bf16(a[mi], bb[ni], acc[mi][ni], 0, 0, 0); \
      __builtin_amdgcn_s_setprio(0);                                                    \
    }                                                                                   \
  } while (0)

// stage tile T+1 into BS, compute tile T from BC, drain, barrier.
// (Drain is hidden by the co-resident second block on the CU.)
#define ITER(T, BC, BS)                                      \
  do {                                                       \
    STAGE((T) + 1, BS);                                      \
    COMPUTE(BC);                                             \
    asm volatile("s_waitcnt vmcnt(0)" ::: "memory");         \
    __builtin_amdgcn_s_barrier();                            \
  } while (0)

  STAGE(0, 0);
  asm volatile("s_waitcnt vmcnt(0)" ::: "memory");
  __builtin_amdgcn_s_barrier();

  for (int t = 0; t < 62; t += 2) {
    ITER(t, 0, 1);
    ITER(t + 1, 1, 0);
  }
  ITER(62, 0, 1);  // stages tile 63 -> buf1, computes tile 62
  COMPUTE(1);      // tile 63
#undef ITER
#undef STAGE
#undef COMPUTE

  // fused epilogue: tanh(u + hi) * Wcw, reduce over cols, atomicAdd.
  // C/D: col(h) = ln31, row(n) = (reg&3) + 8*(reg>>2) + 4*kh
  const int b_idx = row0 >> 9;
  float wc[2], hv[2];
#pragma unroll
  for (int ni = 0; ni < 2; ++ni) {
    const int h = col0 + wn * 64 + ni * 32 + ln31;
    wc[ni] = (h < H) ? Wcw[h] : 0.f;
    hv[ni] = (h < H) ? hi[b_idx * H + h] : 0.f;
  }
#pragma unroll
  for (int mi = 0; mi < 2; ++mi) {
#pragma unroll
    for (int reg = 0; reg < 16; ++reg) {
      float p = wc[0] * tanh_fast(acc[mi][0][reg] + hv[0])
              + wc[1] * tanh_fast(acc[mi][1][reg] + hv[1]);
      p += __shfl_xor(p, 1);
      p += __shfl_xor(p, 2);
      p += __shfl_xor(p, 4);
      p += __shfl_xor(p, 8);
      p += __shfl_xor(p, 16);
      if (ln31 == 0) {
        const int n = row0 + wm * 64 + mi * 32 + (reg & 3) + 8 * (reg >> 2) + 4 * kh;
        atomicAdd(&scores[n], p);
      }
    }
  }
}

// K1 fallback (reg-staged pipeline) for small ws_size.
#define BM 128
#define BN 128
#define BK 32
#define NT 63
__global__ __launch_bounds__(256) void k_scores(const float* __restrict__ ctx,
                                                const float* __restrict__ Wa,
                                                const float* __restrict__ hi,
                                                const float* __restrict__ Wcw,
                                                float* __restrict__ scores) {
  __shared__ unsigned short As[2][BM][BK];
  __shared__ unsigned short Bs[2][BN][BK];

  const int bid = blockIdx.x;
  const int swz = (bid & 7) * 256 + (bid >> 3);
  const int row0 = (swz >> 3) * BM;
  const int col0 = (swz & 7) * BN;

  const int tid = threadIdx.x;
  const int lane = tid & 63;
  const int wid = tid >> 6;
  const int wm = wid >> 1;
  const int wn = wid & 1;
  const int fr = lane & 15;
  const int fq = lane >> 4;

  const int trow = tid >> 1;
  const int thalf = tid & 1;

  f32x4 acc[4][4];
#pragma unroll
  for (int i = 0; i < 4; ++i)
#pragma unroll
    for (int j = 0; j < 4; ++j) acc[i][j] = (f32x4){0.f, 0.f, 0.f, 0.f};

  const float* aptr = ctx + (size_t)(row0 + trow) * D + thalf * 16;
  const int hB = col0 + trow;
  const bool bvalid = (hB < H);
  const float* bptr = Wa + (size_t)(bvalid ? hB : 0) * D + thalf * 16;

  float4 ra[4], rb[4];

#define LOADT(T)                                                     \
  do {                                                               \
    const int base = (T) * BK + thalf * 16;                          \
    _Pragma("unroll")                                                \
    for (int q = 0; q < 4; ++q) {                                    \
      const int kk = base + q * 4;                                   \
      if (kk < D) {                                                  \
        ra[q] = *(const float4*)(aptr + (T) * BK + q * 4);           \
        if (bvalid) rb[q] = *(const float4*)(bptr + (T) * BK + q * 4); \
      }                                                              \
    }                                                                \
  } while (0)

#define CVTW(T, BUF)                                                 \
  do {                                                               \
    const int base = (T) * BK + thalf * 16;                          \
    unsigned short ta[16], tb[16];                                   \
    _Pragma("unroll")                                                \
    for (int q = 0; q < 4; ++q) {                                    \
      const int kk = base + q * 4;                                   \
      const bool v = (kk < D);                                       \
      ta[q * 4 + 0] = v ? f2bf(ra[q].x) : 0;                         \
      ta[q * 4 + 1] = v ? f2bf(ra[q].y) : 0;                         \
      ta[q * 4 + 2] = v ? f2bf(ra[q].z) : 0;                         \
      ta[q * 4 + 3] = v ? f2bf(ra[q].w) : 0;                         \
      const bool vb = v && bvalid;                                   \
      tb[q * 4 + 0] = vb ? f2bf(rb[q].x) : 0;                        \
      tb[q * 4 + 1] = vb ? f2bf(rb[q].y) : 0;                        \
      tb[q * 4 + 2] = vb ? f2bf(rb[q].z) : 0;                        \
      tb[q * 4 + 3] = vb ? f2bf(rb[q].w) : 0;                        \
    }                                                                \
    *(short8*)&As[BUF][trow][thalf * 16]     = *(short8*)&ta[0];     \
    *(short8*)&As[BUF][trow][thalf * 16 + 8] = *(short8*)&ta[8];     \
    *(short8*)&Bs[BUF][trow][thalf * 16]     = *(short8*)&tb[0];     \
    *(short8*)&Bs[BUF][trow][thalf * 16 + 8] = *(short8*)&tb[8];     \
  } while (0)

  LOADT(0);
  CVTW(0, 0);
  LOADT(1);
  __syncthreads();

  int cur = 0;
  for (int t = 0; t < NT; ++t) {
    short8 a[4], bbf[4];
#pragma unroll
    for (int mi = 0; mi < 4; ++mi)
      a[mi] = *(const short8*)&As[cur][wm * 64 + mi * 16 + fr][fq * 8];
#pragma unroll
    for (int ni = 0; ni < 4; ++ni)
      bbf[ni] = *(const short8*)&Bs[cur][wn * 64 + ni * 16 + fr][fq * 8];
#pragma unroll
    for (int mi = 0; mi < 4; ++mi)
#pragma unroll
      for (int ni = 0; ni < 4; ++ni)
        acc[mi][ni] = __builtin_amdgcn_mfma_f32_16x16x32_bf16(a[mi], bbf[ni], acc[mi][ni], 0, 0, 0);

    if (t + 1 < NT) {
      CVTW(t + 1, cur ^ 1);
      if (t + 2 < NT) LOADT(t + 2);
    }
    __syncthreads();
    cur ^= 1;
  }
#undef LOADT
#undef CVTW

  const int b_idx = row0 >> 9;
  float wcv[4], hiv[4];
#pragma unroll
  for (int ni = 0; ni < 4; ++ni) {
    const int h = col0 + wn * 64 + ni * 16 + fr;
    wcv[ni] = (h < H) ? Wcw[h] : 0.f;
    hiv[ni] = (h < H) ? hi[b_idx * H + h] : 0.f;
  }
#pragma unroll
  for (int mi = 0; mi < 4; ++mi) {
#pragma unroll
    for (int r = 0; r < 4; ++r) {
      float p = 0.f;
#pragma unroll
      for (int ni = 0; ni < 4; ++ni)
        p += wcv[ni] * tanhf(acc[mi][ni][r] + hiv[ni]);
      p += __shfl_xor(p, 1);
      p += __shfl_xor(p, 2);
      p += __shfl_xor(p, 4);
      p += __shfl_xor(p, 8);
      if (fr == 0)
        atomicAdd(&scores[row0 + wm * 64 + mi * 16 + fq * 4 + r], p);
    }
  }
}

// K2 (fallback path only): masked softmax over S per batch row
__global__ __launch_bounds__(256) void k_softmax(const float* __restrict__ scores,
                                                 const int* __restrict__ mask,
                                                 const float* __restrict__ Wcb,
                                                 float* __restrict__ probs) {
  __shared__ float buf[S];
  __shared__ float rbuf[256];
  const int b = blockIdx.x;
  const float bias = Wcb[0];
  float mx = -3.4e38f;
  for (int s = threadIdx.x; s < S; s += 256) {
    float a = mask[b * S + s] ? -1e6f : (scores[b * S + s] + bias);
    buf[s] = a;
    mx = fmaxf(mx, a);
  }
  rbuf[threadIdx.x] = mx;
  __syncthreads();
  for (int w = 128; w > 0; w >>= 1) {
    if (threadIdx.x < w) rbuf[threadIdx.x] = fmaxf(rbuf[threadIdx.x], rbuf[threadIdx.x + w]);
    __syncthreads();
  }
  mx = rbuf[0];
  __syncthreads();
  float sum = 0.f;
  for (int s = threadIdx.x; s < S; s += 256) {
    float e = expf(buf[s] - mx);
    buf[s] = e;
    sum += e;
  }
  rbuf[threadIdx.x] = sum;
  __syncthreads();
  for (int w = 128; w > 0; w >>= 1) {
    if (threadIdx.x < w) rbuf[threadIdx.x] += rbuf[threadIdx.x + w];
    __syncthreads();
  }
  const float inv = 1.f / rbuf[0];
  for (int s = threadIdx.x; s < S; s += 256) probs[b * S + s] = buf[s] * inv;
}

// K3 fast: fused softmax + weighted sum on tiled bf16 chunks. grid (63, B).
__global__ __launch_bounds__(256) void k_wsum_sm(const unsigned short* __restrict__ ctxb,
                                                 const float* __restrict__ scores,
                                                 const int* __restrict__ mask,
                                                 const float* __restrict__ Wcb,
                                                 float* __restrict__ ws2) {
  __shared__ float sp[S];
  __shared__ float red[8];
  const int t = blockIdx.x;
  const int b = blockIdx.y;
  const int tid = threadIdx.x;
  const int p = tid >> 6;     // wave / plane 0..3
  const int lane = tid & 63;
  const float bias = Wcb[0];

  float a0 = mask[b * S + tid] ? -1e6f : (scores[b * S + tid] + bias);
  float a1 = mask[b * S + tid + 256] ? -1e6f : (scores[b * S + tid + 256] + bias);
  float m = fmaxf(a0, a1);
#pragma unroll
  for (int o = 32; o; o >>= 1) m = fmaxf(m, __shfl_xor(m, o));
  if (lane == 0) red[p] = m;
  __syncthreads();
  m = fmaxf(fmaxf(red[0], red[1]), fmaxf(red[2], red[3]));
  float e0 = expf(a0 - m), e1 = expf(a1 - m);
  float s = e0 + e1;
#pragma unroll
  for (int o = 32; o; o >>= 1) s += __shfl_xor(s, o);
  if (lane == 0) red[4 + p] = s;
  __syncthreads();
  const float inv = 1.f / (red[4] + red[5] + red[6] + red[7]);
  sp[tid] = e0 * inv;
  sp[tid + 256] = e1 * inv;
  __syncthreads();

  float acc[8];
#pragma unroll
  for (int e = 0; e < 8; ++e) acc[e] = 0.f;
#pragma unroll
  for (int rt = 0; rt < 2; ++rt) {
    const unsigned short* chunk = ctxb + ((size_t)(b * 2 + rt) * 64 + t) * 8192;
#pragma unroll
    for (int half = 0; half < 4; ++half) {
      const int row = half * 64 + lane;
      short8 v = *(const short8*)&chunk[(p * 256 + row) * 8];
      const float pv = sp[rt * 256 + row];
#pragma unroll
      for (int e = 0; e < 8; ++e) acc[e] += pv * bf2f((unsigned short)v[e]);
    }
  }
#pragma unroll
  for (int o = 32; o; o >>= 1)
#pragma unroll
    for (int e = 0; e < 8; ++e) acc[e] += __shfl_xor(acc[e], o);
  const int d0 = t * 32 + p * 8;
  if (lane == 0 && d0 < D) {
#pragma unroll
    for (int e = 0; e < 8; ++e) ws2[(size_t)b * D + d0 + e] = acc[e];
  }
}

// K3 fallback
__global__ __launch_bounds__(256) void k_wsum(const float* __restrict__ ctx,
                                              const float* __restrict__ probs,
                                              float* __restrict__ ws2) {
  __shared__ float p[S];
  const int b = blockIdx.y;
  const int d = blockIdx.x * 256 + threadIdx.x;
  for (int s = threadIdx.x; s < S; s += 256) p[s] = probs[b * S + s];
  __syncthreads();
  if (d < D) {
    float acc = 0.f;
    for (int s = 0; s < S; ++s) acc += p[s] * ctx[(size_t)(b * S + s) * D + d];
    ws2[b * D + d] = acc;
  }
}

// K4a: dense partials, k-split. grid (250, KS).
__global__ __launch_bounds__(256) void k_dense_part(const float* __restrict__ ws2,
                                                    const float* __restrict__ Dw,
                                                    float* __restrict__ partial) {
  __shared__ float sw[64][201];
  const int tid = threadIdx.x;
  const int ks = blockIdx.y;
  const int k0 = ks * 200;
  for (int idx = tid; idx < 64 * 200; idx += 256) {
    const int b = idx / 200, k = idx - b * 200;
    sw[b][k] = ws2[(size_t)b * D + k0 + k];
  }
  __syncthreads();
  const int h = blockIdx.x * 4 + (tid >> 6);
  const int lane = tid & 63;
  const float* wrow = Dw + (size_t)h * D + k0;
  float acc = 0.f;
#pragma unroll 8
  for (int k = 0; k < 200; ++k) acc += wrow[k] * sw[lane][k];
  partial[((size_t)ks * 64 + lane) * 1000 + h] = acc;
}

// K4b: reduce partials + bias
__global__ __launch_bounds__(256) void k_dense_red(const float* __restrict__ partial,
                                                   const float* __restrict__ Db,
                                                   float* __restrict__ out) {
  const int idx = blockIdx.x * 256 + threadIdx.x;  // b*1000 + h
  const int h = idx % 1000;
  float acc = Db[h];
#pragma unroll
  for (int ks = 0; ks < KS; ++ks) acc += partial[(size_t)ks * 64000 + idx];
  out[idx] = acc;
}

// K4 fallback
__global__ __launch_bounds__(256) void k_dense(const float* __restrict__ ws2,
                                               const float* __restrict__ Dw,
                                               const float* __restrict__ Db,
                                               float* __restrict__ out) {
  __shared__ float v[D];
  const int b = blockIdx.y;
  const int h = blockIdx.x * 256 + threadIdx.x;
  for (int d = threadIdx.x; d < D; d += 256) v[d] = ws2[b * D + d];
  __syncthreads();
  if (h < H) {
    const float* w = Dw + (size_t)h * D;
    float acc = 0.f;
    for (int d = 0; d < D; ++d) acc += w[d] * v[d];
    out[b * H + h] = acc + Db[h];
  }
}

extern "C" void kernel_launch(void* const* d_in, const int* in_sizes, int n_in,
                              void* d_out, int out_size, void* d_ws, size_t ws_size,
                              hipStream_t stream) {
  const float* dec = (const float*)d_in[0];   // (1,B,H)
  const float* ctx = (const float*)d_in[1];   // (B,S,D)
  const int*   mask = (const int*)d_in[2];    // (B,S,1)
  const float* Wa  = (const float*)d_in[3];   // (H,D)
  const float* Wb  = (const float*)d_in[4];   // (H,H)
  const float* Wcw = (const float*)d_in[5];   // (1,H)
  const float* Wcb = (const float*)d_in[6];   // (1,)
  const float* Dw  = (const float*)d_in[7];   // (H,D)
  const float* Db  = (const float*)d_in[8];   // (H,)
  float* out = (float*)d_out;                 // (B,1,H)

  float* hi     = (float*)d_ws;     // B*H
  float* scores = hi + B * H;       // B*S
  float* probs  = scores + B * S;   // B*S (fallback path only)
  float* ws2    = probs + B * S;    // B*D
  const size_t float_words = (size_t)B * H + 2 * B * S + B * D;  // 257536 (16B-aligned)
  unsigned short* ctx_b = (unsigned short*)((float*)d_ws + float_words);
  unsigned short* wa_b  = ctx_b + (size_t)MP * KP;
  float* dec_t  = (float*)ctx_b;   // overlay: used before ctx_b is written
  float* partial = (float*)ctx_b;  // overlay: used after ctx_b is dead (after k_wsum_sm)
  const size_t need = float_words * 4 + ((size_t)MP * KP + (size_t)NP * KP) * 2;

  hipMemsetAsync(scores, 0, B * S * sizeof(float), stream);
  if (ws_size >= need) {
    k_dect<<<250, 256, 0, stream>>>(dec, dec_t);
    k_hidden2<<<250, 256, 0, stream>>>(dec_t, Wb, hi);
    k_cvt2<<<dim3(132, 8), 256, 0, stream>>>(ctx, Wa, ctx_b, wa_b);  // overwrites dec_t region (done)
    k_scores_fast<<<512, 1024, 0, stream>>>(ctx_b, wa_b, hi, Wcw, scores);
    k_wsum_sm<<<dim3(63, B), 256, 0, stream>>>(ctx_b, scores, mask, Wcb, ws2);
    k_dense_part<<<dim3(250, KS), 256, 0, stream>>>(ws2, Dw, partial);  // partial overlays ctx_b (now dead)
    k_dense_red<<<250, 256, 0, stream>>>(partial, Db, out);
  } else {
    k_hidden<<<dim3(250, B), 256, 0, stream>>>(dec, Wb, hi);
    k_scores<<<2048, 256, 0, stream>>>(ctx, Wa, hi, Wcw, scores);
    k_softmax<<<B, 256, 0, stream>>>(scores, mask, Wcb, probs);
    k_wsum<<<dim3((D + 255) / 256, B), 256, 0, stream>>>(ctx, probs, ws2);
    k_dense<<<dim3((H + 255) / 256, B), 256, 0, stream>>>(ws2, Dw, Db, out);
  }
}

// Round 11
// 397.690 us; speedup vs baseline: 8.4796x; 8.4796x over previous
//
#include <hip/hip_runtime.h>
#include <hip/hip_bf16.h>

#define H 1000
#define B 64
#define S 512
#define D 2000   // 2H
#define KP 2048  // padded K
#define NP 1024  // padded N (h dim)
#define MP 32768 // B*S
#define KS 10    // k-splits for dense

typedef __attribute__((ext_vector_type(8))) short short8;
typedef __attribute__((ext_vector_type(4))) float f32x4;
typedef __attribute__((ext_vector_type(16))) float f32x16;

__device__ inline unsigned short f2bf(float f) {
  __hip_bfloat16 h = __float2bfloat16(f);  // RNE
  union { __hip_bfloat16 h; unsigned short u; } c; c.h = h;
  return c.u;
}
__device__ inline float bf2f(unsigned short u) {
  union { unsigned u; float f; } x; x.u = ((unsigned)u) << 16;
  return x.f;
}
// exact at +/-inf; ~1e-7 rel err; much cheaper than tanhf
__device__ inline float tanh_fast(float x) {
  float e2 = __expf(2.f * x);
  return 1.f - 2.f / (e2 + 1.f);
}

// K0a: dec (B,H) -> dec_t (H,B)
__global__ __launch_bounds__(256) void k_dect(const float* __restrict__ dec,
                                              float* __restrict__ dec_t) {
  const int d = blockIdx.x * 4 + (threadIdx.x >> 6);
  const int b = threadIdx.x & 63;
  dec_t[d * 64 + b] = dec[b * H + d];
}

// K0b: hidden_in[b,h] = sum_d W_b[h,d] * dec[b,d]. Wave per h, lane = b.
__global__ __launch_bounds__(256) void k_hidden2(const float* __restrict__ dec_t,
                                                 const float* __restrict__ Wb,
                                                 float* __restrict__ hi) {
  const int h = blockIdx.x * 4 + (threadIdx.x >> 6);
  const int lane = threadIdx.x & 63;
  const float* w = Wb + (size_t)h * H;
  float acc = 0.f;
#pragma unroll 4
  for (int d = 0; d < H; ++d) acc += w[d] * dec_t[d * 64 + lane];
  hi[lane * H + h] = acc;
}

// K0 fallback
__global__ __launch_bounds__(256) void k_hidden(const float* __restrict__ dec,
                                                const float* __restrict__ Wb,
                                                float* __restrict__ hi) {
  __shared__ float sdec[H];
  const int b = blockIdx.y;
  const int h = blockIdx.x * 4 + (threadIdx.x >> 6);
  const int lane = threadIdx.x & 63;
  for (int d = threadIdx.x; d < H; d += 256) sdec[d] = dec[b * H + d];
  __syncthreads();
  const float* w = Wb + (size_t)h * H;
  float acc = 0.f;
  for (int d = lane; d < H; d += 64) acc += w[d] * sdec[d];
  for (int o = 32; o; o >>= 1) acc += __shfl_xor(acc, o);
  if (lane == 0) hi[b * H + h] = acc;
}

// Pre-pass (both inputs in one launch): fp32 row-major [rows][2000] -> bf16 TILED
// chunks [p(4)][row(256)][8], chunk base (rp*64+t)*8192. Direct reg->global,
// no LDS, no barriers. grid (132, 8): x<128 -> ctx panel, else Wa panel.
__global__ __launch_bounds__(256) void k_cvt2(const float* __restrict__ ctx,
                                              const float* __restrict__ wa,
                                              unsigned short* __restrict__ ctx_b,
                                              unsigned short* __restrict__ wa_b) {
  const int bp = blockIdx.x;
  const float* src;
  unsigned short* dst;
  int valid_rows, rp;
  if (bp < 128) { src = ctx; dst = ctx_b; valid_rows = MP; rp = bp; }
  else          { src = wa;  dst = wa_b;  valid_rows = H;  rp = bp - 128; }
  const int tid = threadIdx.x;
  const int r0 = tid >> 2;   // 0..63
  const int kq = tid & 3;    // plane
  const int t0 = blockIdx.y * 8;
  for (int tt = 0; tt < 8; ++tt) {
    const int t = t0 + tt;
    const int gcol = t * 32 + kq * 8;
    unsigned short* ob = dst + ((size_t)rp * 64 + t) * 8192;
#pragma unroll
    for (int w = 0; w < 4; ++w) {
      const int grow = rp * 256 + r0 + w * 64;
      unsigned short v[8];
      if (grow < valid_rows && gcol + 8 <= D) {
        const float* p = src + (size_t)grow * D + gcol;
        float4 x = *(const float4*)p;
        float4 y = *(const float4*)(p + 4);
        v[0] = f2bf(x.x); v[1] = f2bf(x.y); v[2] = f2bf(x.z); v[3] = f2bf(x.w);
        v[4] = f2bf(y.x); v[5] = f2bf(y.y); v[6] = f2bf(y.z); v[7] = f2bf(y.w);
      } else {
#pragma unroll
        for (int z = 0; z < 8; ++z) v[z] = 0;
      }
      *(short8*)(ob + (kq * 256 + r0 + w * 64) * 8) = *(short8*)&v[0];
    }
  }
}

// K1 fast (round-9 proven config): 256x256 tile, 16 waves (4x4), mfma_32x32x16,
// wave tile 64x64 (2x2). 3-buffer depth-2 counted-vmcnt pipeline, literal indices.
__global__ __launch_bounds__(1024) void k_scores_fast(const unsigned short* __restrict__ ctxb,
                                                      const unsigned short* __restrict__ wab,
                                                      const float* __restrict__ hi,
                                                      const float* __restrict__ Wcw,
                                                      float* __restrict__ scores) {
  __shared__ unsigned short As[3][8192];
  __shared__ unsigned short Bs[3][8192];

  // bijective XCD swizzle: 512 blocks = 8 chunks of 64; 4 ctiles of one rtile
  // adjacent -> A-panel L2 reuse.
  const int bid = blockIdx.x;
  const int swz = (bid & 7) * 64 + (bid >> 3);
  const int rtile = swz >> 2;  // 0..127
  const int ctile = swz & 3;   // 0..3
  const int row0 = rtile * 256;
  const int col0 = ctile * 256;

  const int tid = threadIdx.x;
  const int lane = tid & 63;
  const int wid = tid >> 6;        // 0..15
  const int wm = wid >> 2;         // 0..3 (row quarter)
  const int wn = wid & 3;          // 0..3 (col quarter)
  const int ln31 = lane & 31;
  const int kh = lane >> 5;        // 0..1

  const unsigned short* ga = ctxb + (size_t)rtile * (64 * 8192);
  const unsigned short* gb = wab + (size_t)ctile * (64 * 8192);

  f32x16 acc[2][2];
#pragma unroll
  for (int i = 0; i < 2; ++i)
#pragma unroll
    for (int j = 0; j < 2; ++j)
#pragma unroll
      for (int r = 0; r < 16; ++r) acc[i][j][r] = 0.f;

#define STAGE(T, BUF)                                                                                      \
  do {                                                                                                     \
    const unsigned short* pa = ga + (size_t)(T) * 8192 + tid * 8;                                          \
    const unsigned short* pb = gb + (size_t)(T) * 8192 + tid * 8;                                          \
    __builtin_amdgcn_global_load_lds((const __attribute__((address_space(1))) unsigned int*)pa,            \
                                     (__attribute__((address_space(3))) unsigned int*)&As[BUF][tid * 8],   \
                                     16, 0, 0);                                                            \
    __builtin_amdgcn_global_load_lds((const __attribute__((address_space(1))) unsigned int*)pb,            \
                                     (__attribute__((address_space(3))) unsigned int*)&Bs[BUF][tid * 8],   \
                                     16, 0, 0);                                                            \
  } while (0)

  // plane p = ks*2 + kh; addr(shorts) = p*2048 + row*8
  const int abase = kh * 2048 + (wm * 64 + ln31) * 8;
  const int bbase = kh * 2048 + (wn * 64 + ln31) * 8;

#define COMPUTE(BI)                                                                     \
  do {                                                                                  \
    _Pragma("unroll")                                                                   \
    for (int ks = 0; ks < 2; ++ks) {                                                    \
      short8 a[2], bb[2];                                                               \
      _Pragma("unroll")                                                                 \
      for (int mi = 0; mi < 2; ++mi)                                                    \
        a[mi] = *(const short8*)&As[BI][abase + ks * 4096 + mi * 256];                  \
      _Pragma("unroll")                                                                 \
      for (int ni = 0; ni < 2; ++ni)                                                    \
        bb[ni] = *(const short8*)&Bs[BI][bbase + ks * 4096 + ni * 256];                 \
      __builtin_amdgcn_s_setprio(1);                                                    \
      _Pragma("unroll")                                                                 \
      for (int mi = 0; mi < 2; ++mi)                                                    \
        _Pragma("unroll")                                                               \
        for (int ni = 0; ni < 2; ++ni)                                                  \
          acc[mi][ni] = __builtin_amdgcn_mfma_f32_32x32x16_bf16(a[mi], bb[ni], acc[mi][ni], 0, 0, 0); \
      __builtin_amdgcn_s_setprio(0);                                                    \
    }                                                                                   \
  } while (0)

#define ITER(T, BC, BS)                                      \
  do {                                                       \
    STAGE((T) + 2, BS);                                      \
    COMPUTE(BC);                                             \
    asm volatile("s_waitcnt vmcnt(2)" ::: "memory");         \
    __builtin_amdgcn_s_barrier();                            \
  } while (0)

  STAGE(0, 0);
  STAGE(1, 1);
  asm volatile("s_waitcnt vmcnt(2)" ::: "memory");
  __builtin_amdgcn_s_barrier();

  for (int t = 0; t < 60; t += 3) {
    ITER(t, 0, 2);
    ITER(t + 1, 1, 0);
    ITER(t + 2, 2, 1);
  }
  ITER(60, 0, 2);  // stages tile 62 -> buf2
  ITER(61, 1, 0);  // stages tile 63 -> buf0
  COMPUTE(2);      // t = 62
  asm volatile("s_waitcnt vmcnt(0)" ::: "memory");
  __builtin_amdgcn_s_barrier();
  COMPUTE(0);      // t = 63
#undef ITER
#undef STAGE
#undef COMPUTE

  // fused epilogue: tanh(u + hi) * Wcw, reduce over cols, atomicAdd.
  // C/D: col(h) = ln31, row(n) = (reg&3) + 8*(reg>>2) + 4*kh
  const int b_idx = row0 >> 9;
  float wc[2], hv[2];
#pragma unroll
  for (int ni = 0; ni < 2; ++ni) {
    const int h = col0 + wn * 64 + ni * 32 + ln31;
    wc[ni] = (h < H) ? Wcw[h] : 0.f;
    hv[ni] = (h < H) ? hi[b_idx * H + h] : 0.f;
  }
#pragma unroll
  for (int mi = 0; mi < 2; ++mi) {
#pragma unroll
    for (int reg = 0; reg < 16; ++reg) {
      float p = wc[0] * tanh_fast(acc[mi][0][reg] + hv[0])
              + wc[1] * tanh_fast(acc[mi][1][reg] + hv[1]);
      p += __shfl_xor(p, 1);
      p += __shfl_xor(p, 2);
      p += __shfl_xor(p, 4);
      p += __shfl_xor(p, 8);
      p += __shfl_xor(p, 16);
      if (ln31 == 0) {
        const int n = row0 + wm * 64 + mi * 32 + (reg & 3) + 8 * (reg >> 2) + 4 * kh;
        atomicAdd(&scores[n], p);
      }
    }
  }
}

// K1 fallback (reg-staged pipeline) for small ws_size.
#define BM 128
#define BN 128
#define BK 32
#define NT 63
__global__ __launch_bounds__(256) void k_scores(const float* __restrict__ ctx,
                                                const float* __restrict__ Wa,
                                                const float* __restrict__ hi,
                                                const float* __restrict__ Wcw,
                                                float* __restrict__ scores) {
  __shared__ unsigned short As[2][BM][BK];
  __shared__ unsigned short Bs[2][BN][BK];

  const int bid = blockIdx.x;
  const int swz = (bid & 7) * 256 + (bid >> 3);
  const int row0 = (swz >> 3) * BM;
  const int col0 = (swz & 7) * BN;

  const int tid = threadIdx.x;
  const int lane = tid & 63;
  const int wid = tid >> 6;
  const int wm = wid >> 1;
  const int wn = wid & 1;
  const int fr = lane & 15;
  const int fq = lane >> 4;

  const int trow = tid >> 1;
  const int thalf = tid & 1;

  f32x4 acc[4][4];
#pragma unroll
  for (int i = 0; i < 4; ++i)
#pragma unroll
    for (int j = 0; j < 4; ++j) acc[i][j] = (f32x4){0.f, 0.f, 0.f, 0.f};

  const float* aptr = ctx + (size_t)(row0 + trow) * D + thalf * 16;
  const int hB = col0 + trow;
  const bool bvalid = (hB < H);
  const float* bptr = Wa + (size_t)(bvalid ? hB : 0) * D + thalf * 16;

  float4 ra[4], rb[4];

#define LOADT(T)                                                     \
  do {                                                               \
    const int base = (T) * BK + thalf * 16;                          \
    _Pragma("unroll")                                                \
    for (int q = 0; q < 4; ++q) {                                    \
      const int kk = base + q * 4;                                   \
      if (kk < D) {                                                  \
        ra[q] = *(const float4*)(aptr + (T) * BK + q * 4);           \
        if (bvalid) rb[q] = *(const float4*)(bptr + (T) * BK + q * 4); \
      }                                                              \
    }                                                                \
  } while (0)

#define CVTW(T, BUF)                                                 \
  do {                                                               \
    const int base = (T) * BK + thalf * 16;                          \
    unsigned short ta[16], tb[16];                                   \
    _Pragma("unroll")                                                \
    for (int q = 0; q < 4; ++q) {                                    \
      const int kk = base + q * 4;                                   \
      const bool v = (kk < D);                                       \
      ta[q * 4 + 0] = v ? f2bf(ra[q].x) : 0;                         \
      ta[q * 4 + 1] = v ? f2bf(ra[q].y) : 0;                         \
      ta[q * 4 + 2] = v ? f2bf(ra[q].z) : 0;                         \
      ta[q * 4 + 3] = v ? f2bf(ra[q].w) : 0;                         \
      const bool vb = v && bvalid;                                   \
      tb[q * 4 + 0] = vb ? f2bf(rb[q].x) : 0;                        \
      tb[q * 4 + 1] = vb ? f2bf(rb[q].y) : 0;                        \
      tb[q * 4 + 2] = vb ? f2bf(rb[q].z) : 0;                        \
      tb[q * 4 + 3] = vb ? f2bf(rb[q].w) : 0;                        \
    }                                                                \
    *(short8*)&As[BUF][trow][thalf * 16]     = *(short8*)&ta[0];     \
    *(short8*)&As[BUF][trow][thalf * 16 + 8] = *(short8*)&ta[8];     \
    *(short8*)&Bs[BUF][trow][thalf * 16]     = *(short8*)&tb[0];     \
    *(short8*)&Bs[BUF][trow][thalf * 16 + 8] = *(short8*)&tb[8];     \
  } while (0)

  LOADT(0);
  CVTW(0, 0);
  LOADT(1);
  __syncthreads();

  int cur = 0;
  for (int t = 0; t < NT; ++t) {
    short8 a[4], bbf[4];
#pragma unroll
    for (int mi = 0; mi < 4; ++mi)
      a[mi] = *(const short8*)&As[cur][wm * 64 + mi * 16 + fr][fq * 8];
#pragma unroll
    for (int ni = 0; ni < 4; ++ni)
      bbf[ni] = *(const short8*)&Bs[cur][wn * 64 + ni * 16 + fr][fq * 8];
#pragma unroll
    for (int mi = 0; mi < 4; ++mi)
#pragma unroll
      for (int ni = 0; ni < 4; ++ni)
        acc[mi][ni] = __builtin_amdgcn_mfma_f32_16x16x32_bf16(a[mi], bbf[ni], acc[mi][ni], 0, 0, 0);

    if (t + 1 < NT) {
      CVTW(t + 1, cur ^ 1);
      if (t + 2 < NT) LOADT(t + 2);
    }
    __syncthreads();
    cur ^= 1;
  }
#undef LOADT
#undef CVTW

  const int b_idx = row0 >> 9;
  float wcv[4], hiv[4];
#pragma unroll
  for (int ni = 0; ni < 4; ++ni) {
    const int h = col0 + wn * 64 + ni * 16 + fr;
    wcv[ni] = (h < H) ? Wcw[h] : 0.f;
    hiv[ni] = (h < H) ? hi[b_idx * H + h] : 0.f;
  }
#pragma unroll
  for (int mi = 0; mi < 4; ++mi) {
#pragma unroll
    for (int r = 0; r < 4; ++r) {
      float p = 0.f;
#pragma unroll
      for (int ni = 0; ni < 4; ++ni)
        p += wcv[ni] * tanhf(acc[mi][ni][r] + hiv[ni]);
      p += __shfl_xor(p, 1);
      p += __shfl_xor(p, 2);
      p += __shfl_xor(p, 4);
      p += __shfl_xor(p, 8);
      if (fr == 0)
        atomicAdd(&scores[row0 + wm * 64 + mi * 16 + fq * 4 + r], p);
    }
  }
}

// K2 (fallback path only): masked softmax over S per batch row
__global__ __launch_bounds__(256) void k_softmax(const float* __restrict__ scores,
                                                 const int* __restrict__ mask,
                                                 const float* __restrict__ Wcb,
                                                 float* __restrict__ probs) {
  __shared__ float buf[S];
  __shared__ float rbuf[256];
  const int b = blockIdx.x;
  const float bias = Wcb[0];
  float mx = -3.4e38f;
  for (int s = threadIdx.x; s < S; s += 256) {
    float a = mask[b * S + s] ? -1e6f : (scores[b * S + s] + bias);
    buf[s] = a;
    mx = fmaxf(mx, a);
  }
  rbuf[threadIdx.x] = mx;
  __syncthreads();
  for (int w = 128; w > 0; w >>= 1) {
    if (threadIdx.x < w) rbuf[threadIdx.x] = fmaxf(rbuf[threadIdx.x], rbuf[threadIdx.x + w]);
    __syncthreads();
  }
  mx = rbuf[0];
  __syncthreads();
  float sum = 0.f;
  for (int s = threadIdx.x; s < S; s += 256) {
    float e = expf(buf[s] - mx);
    buf[s] = e;
    sum += e;
  }
  rbuf[threadIdx.x] = sum;
  __syncthreads();
  for (int w = 128; w > 0; w >>= 1) {
    if (threadIdx.x < w) rbuf[threadIdx.x] += rbuf[threadIdx.x + w];
    __syncthreads();
  }
  const float inv = 1.f / rbuf[0];
  for (int s = threadIdx.x; s < S; s += 256) probs[b * S + s] = buf[s] * inv;
}

// K3 fast: fused softmax + weighted sum on tiled bf16 chunks. grid (63, B).
__global__ __launch_bounds__(256) void k_wsum_sm(const unsigned short* __restrict__ ctxb,
                                                 const float* __restrict__ scores,
                                                 const int* __restrict__ mask,
                                                 const float* __restrict__ Wcb,
                                                 float* __restrict__ ws2) {
  __shared__ float sp[S];
  __shared__ float red[8];
  const int t = blockIdx.x;
  const int b = blockIdx.y;
  const int tid = threadIdx.x;
  const int p = tid >> 6;     // wave / plane 0..3
  const int lane = tid & 63;
  const float bias = Wcb[0];

  float a0 = mask[b * S + tid] ? -1e6f : (scores[b * S + tid] + bias);
  float a1 = mask[b * S + tid + 256] ? -1e6f : (scores[b * S + tid + 256] + bias);
  float m = fmaxf(a0, a1);
#pragma unroll
  for (int o = 32; o; o >>= 1) m = fmaxf(m, __shfl_xor(m, o));
  if (lane == 0) red[p] = m;
  __syncthreads();
  m = fmaxf(fmaxf(red[0], red[1]), fmaxf(red[2], red[3]));
  float e0 = expf(a0 - m), e1 = expf(a1 - m);
  float s = e0 + e1;
#pragma unroll
  for (int o = 32; o; o >>= 1) s += __shfl_xor(s, o);
  if (lane == 0) red[4 + p] = s;
  __syncthreads();
  const float inv = 1.f / (red[4] + red[5] + red[6] + red[7]);
  sp[tid] = e0 * inv;
  sp[tid + 256] = e1 * inv;
  __syncthreads();

  float acc[8];
#pragma unroll
  for (int e = 0; e < 8; ++e) acc[e] = 0.f;
#pragma unroll
  for (int rt = 0; rt < 2; ++rt) {
    const unsigned short* chunk = ctxb + ((size_t)(b * 2 + rt) * 64 + t) * 8192;
#pragma unroll
    for (int half = 0; half < 4; ++half) {
      const int row = half * 64 + lane;
      short8 v = *(const short8*)&chunk[(p * 256 + row) * 8];
      const float pv = sp[rt * 256 + row];
#pragma unroll
      for (int e = 0; e < 8; ++e) acc[e] += pv * bf2f((unsigned short)v[e]);
    }
  }
#pragma unroll
  for (int o = 32; o; o >>= 1)
#pragma unroll
    for (int e = 0; e < 8; ++e) acc[e] += __shfl_xor(acc[e], o);
  const int d0 = t * 32 + p * 8;
  if (lane == 0 && d0 < D) {
#pragma unroll
    for (int e = 0; e < 8; ++e) ws2[(size_t)b * D + d0 + e] = acc[e];
  }
}

// K3 fallback
__global__ __launch_bounds__(256) void k_wsum(const float* __restrict__ ctx,
                                              const float* __restrict__ probs,
                                              float* __restrict__ ws2) {
  __shared__ float p[S];
  const int b = blockIdx.y;
  const int d = blockIdx.x * 256 + threadIdx.x;
  for (int s = threadIdx.x; s < S; s += 256) p[s] = probs[b * S + s];
  __syncthreads();
  if (d < D) {
    float acc = 0.f;
    for (int s = 0; s < S; ++s) acc += p[s] * ctx[(size_t)(b * S + s) * D + d];
    ws2[b * D + d] = acc;
  }
}

// K4a: dense partials, k-split. grid (250, KS).
__global__ __launch_bounds__(256) void k_dense_part(const float* __restrict__ ws2,
                                                    const float* __restrict__ Dw,
                                                    float* __restrict__ partial) {
  __shared__ float sw[64][201];
  const int tid = threadIdx.x;
  const int ks = blockIdx.y;
  const int k0 = ks * 200;
  for (int idx = tid; idx < 64 * 200; idx += 256) {
    const int b = idx / 200, k = idx - b * 200;
    sw[b][k] = ws2[(size_t)b * D + k0 + k];
  }
  __syncthreads();
  const int h = blockIdx.x * 4 + (tid >> 6);
  const int lane = tid & 63;
  const float* wrow = Dw + (size_t)h * D + k0;
  float acc = 0.f;
#pragma unroll 8
  for (int k = 0; k < 200; ++k) acc += wrow[k] * sw[lane][k];
  partial[((size_t)ks * 64 + lane) * 1000 + h] = acc;
}

// K4b: reduce partials + bias
__global__ __launch_bounds__(256) void k_dense_red(const float* __restrict__ partial,
                                                   const float* __restrict__ Db,
                                                   float* __restrict__ out) {
  const int idx = blockIdx.x * 256 + threadIdx.x;  // b*1000 + h
  const int h = idx % 1000;
  float acc = Db[h];
#pragma unroll
  for (int ks = 0; ks < KS; ++ks) acc += partial[(size_t)ks * 64000 + idx];
  out[idx] = acc;
}

// K4 fallback
__global__ __launch_bounds__(256) void k_dense(const float* __restrict__ ws2,
                                               const float* __restrict__ Dw,
                                               const float* __restrict__ Db,
                                               float* __restrict__ out) {
  __shared__ float v[D];
  const int b = blockIdx.y;
  const int h = blockIdx.x * 256 + threadIdx.x;
  for (int d = threadIdx.x; d < D; d += 256) v[d] = ws2[b * D + d];
  __syncthreads();
  if (h < H) {
    const float* w = Dw + (size_t)h * D;
    float acc = 0.f;
    for (int d = 0; d < D; ++d) acc += w[d] * v[d];
    out[b * H + h] = acc + Db[h];
  }
}

extern "C" void kernel_launch(void* const* d_in, const int* in_sizes, int n_in,
                              void* d_out, int out_size, void* d_ws, size_t ws_size,
                              hipStream_t stream) {
  const float* dec = (const float*)d_in[0];   // (1,B,H)
  const float* ctx = (const float*)d_in[1];   // (B,S,D)
  const int*   mask = (const int*)d_in[2];    // (B,S,1)
  const float* Wa  = (const float*)d_in[3];   // (H,D)
  const float* Wb  = (const float*)d_in[4];   // (H,H)
  const float* Wcw = (const float*)d_in[5];   // (1,H)
  const float* Wcb = (const float*)d_in[6];   // (1,)
  const float* Dw  = (const float*)d_in[7];   // (H,D)
  const float* Db  = (const float*)d_in[8];   // (H,)
  float* out = (float*)d_out;                 // (B,1,H)

  float* hi     = (float*)d_ws;     // B*H
  float* scores = hi + B * H;       // B*S
  float* probs  = scores + B * S;   // B*S (fallback path only)
  float* ws2    = probs + B * S;    // B*D
  const size_t float_words = (size_t)B * H + 2 * B * S + B * D;  // 257536 (16B-aligned)
  unsigned short* ctx_b = (unsigned short*)((float*)d_ws + float_words);
  unsigned short* wa_b  = ctx_b + (size_t)MP * KP;
  float* dec_t  = (float*)ctx_b;   // overlay: used before ctx_b is written
  float* partial = (float*)ctx_b;  // overlay: used after ctx_b is dead (after k_wsum_sm)
  const size_t need = float_words * 4 + ((size_t)MP * KP + (size_t)NP * KP) * 2;

  hipMemsetAsync(scores, 0, B * S * sizeof(float), stream);
  if (ws_size >= need) {
    k_dect<<<250, 256, 0, stream>>>(dec, dec_t);
    k_hidden2<<<250, 256, 0, stream>>>(dec_t, Wb, hi);
    k_cvt2<<<dim3(132, 8), 256, 0, stream>>>(ctx, Wa, ctx_b, wa_b);  // overwrites dec_t region (done)
    k_scores_fast<<<512, 1024, 0, stream>>>(ctx_b, wa_b, hi, Wcw, scores);
    k_wsum_sm<<<dim3(63, B), 256, 0, stream>>>(ctx_b, scores, mask, Wcb, ws2);
    k_dense_part<<<dim3(250, KS), 256, 0, stream>>>(ws2, Dw, partial);  // partial overlays ctx_b (now dead)
    k_dense_red<<<250, 256, 0, stream>>>(partial, Db, out);
  } else {
    k_hidden<<<dim3(250, B), 256, 0, stream>>>(dec, Wb, hi);
    k_scores<<<2048, 256, 0, stream>>>(ctx, Wa, hi, Wcw, scores);
    k_softmax<<<B, 256, 0, stream>>>(scores, mask, Wcb, probs);
    k_wsum<<<dim3((D + 255) / 256, B), 256, 0, stream>>>(ctx, probs, ws2);
    k_dense<<<dim3((H + 255) / 256, B), 256, 0, stream>>>(ws2, Dw, Db, out);
  }
}